// Round 10
// baseline (264.895 us; speedup 1.0000x reference)
//
#include <hip/hip_runtime.h>

typedef __attribute__((ext_vector_type(8))) short short8;
typedef __attribute__((ext_vector_type(4))) float f32x4;
typedef __attribute__((ext_vector_type(16))) float f32x16;
typedef unsigned short u16;
typedef unsigned int u32;

__device__ __forceinline__ float bf2f(u16 u) {
    union { u32 i; float f; } x;
    x.i = ((u32)u) << 16;
    return x.f;
}

__device__ __forceinline__ u16 f2bf(float f) {
    union { float f; u32 i; } x;
    x.f = f;
    u32 r = x.i + 0x7fffu + ((x.i >> 16) & 1u);  // RNE
    return (u16)(r >> 16);
}

// packed f32x2 -> bf16x2 (RNE), one instruction
__device__ __forceinline__ u32 cvt_pk_bf16(float lo, float hi) {
    u32 d;
    asm("v_cvt_pk_bf16_f32 %0, %1, %2" : "=v"(d) : "v"(lo), "v"(hi));
    return d;
}

// async global->LDS DMA, 16 B/lane. LDS dest = wave-uniform base + lane*16.
__device__ __forceinline__ void gload_lds16(const u16* g, u16* l) {
    __builtin_amdgcn_global_load_lds(
        (const __attribute__((address_space(1))) void*)g,
        (__attribute__((address_space(3))) void*)l, 16, 0, 0);
}

// after pswap(a,b):  a' = lane<32 ? a(own) : b(lane-32)
//                    b' = lane<32 ? a(lane+32) : b(own)
__device__ __forceinline__ void pswap(u32& a, u32& b) {
#if __has_builtin(__builtin_amdgcn_permlane32_swap)
    auto r = __builtin_amdgcn_permlane32_swap(a, b, false, false);
    a = r[0];
    b = r[1];
#else
    const int l = (int)(threadIdx.x & 63);
    const u32 ax = __shfl(a, l ^ 32);
    const u32 bx = __shfl(b, l ^ 32);
    a = (l < 32) ? a : bx;
    b = (l < 32) ? ax : b;
#endif
}

#if __has_builtin(__builtin_amdgcn_exp2f)
#define EXP2F(x) __builtin_amdgcn_exp2f(x)
#else
#define EXP2F(x) exp2f(x)
#endif

// softmax scale folded into K at GEMM1 epilogue: 0.125 * log2(e)
#define K_SCALE 0.18033688f

// ---------------------------------------------------------------------------
// Fused pre-pass: blocks [0,4096): fp32->bf16 convert of x (8192x1024);
// blocks [4096,7168): w_attn [1024][3072] f32 -> wTa [3072][1024] bf16.
// ---------------------------------------------------------------------------
__global__ __launch_bounds__(256) void prep_kernel(const float* __restrict__ x,
                                                   u16* __restrict__ xb,
                                                   const float* __restrict__ w_attn,
                                                   u16* __restrict__ wTa) {
    __shared__ float tile[32][33];
    const int tid = threadIdx.x;
    if (blockIdx.x < 4096) {
        const long i = ((long)blockIdx.x * 256 + tid) * 8;
        f32x4 v0 = *(const f32x4*)(x + i);
        f32x4 v1 = *(const f32x4*)(x + i + 4);
        short8 o;
#pragma unroll
        for (int j = 0; j < 4; ++j) o[j] = (short)f2bf(v0[j]);
#pragma unroll
        for (int j = 0; j < 4; ++j) o[4 + j] = (short)f2bf(v1[j]);
        *(short8*)(xb + i) = o;
    } else {
        const int bid = blockIdx.x - 4096;
        const int nb = (bid % 96) * 32, kb = (bid / 96) * 32;
        const int tx = tid & 31, ty = tid >> 5;  // 32 x 8
#pragma unroll
        for (int i = 0; i < 32; i += 8)
            tile[ty + i][tx] = w_attn[(long)(kb + ty + i) * 3072 + nb + tx];
        __syncthreads();
#pragma unroll
        for (int i = 0; i < 32; i += 8)
            wTa[(long)(nb + ty + i) * 1024 + kb + tx] = f2bf(tile[tx][ty + i]);
    }
}

// ---------------------------------------------------------------------------
// V transpose: qkv V slots [b*2048+t][2048 + h*64 + d] -> vT[bh][d][t]
// ---------------------------------------------------------------------------
__global__ __launch_bounds__(256) void transpose_v(const u16* __restrict__ qkv,
                                                   u16* __restrict__ vT) {
    __shared__ u16 tile[32][33];
    const int tb = blockIdx.x * 32;  // t
    const int db = blockIdx.y * 32;  // d
    const int bh = blockIdx.z;
    const int b = bh >> 4, h = bh & 15;
    const int tx = threadIdx.x, ty = threadIdx.y;  // 32 x 8
#pragma unroll
    for (int i = 0; i < 32; i += 8)
        tile[ty + i][tx] = qkv[((long)b * 2048 + tb + ty + i) * 3072 + 2048 + h * 64 + db + tx];
    __syncthreads();
#pragma unroll
    for (int i = 0; i < 32; i += 8)
        vT[((long)bh * 64 + db + ty + i) * 2048 + tb + tx] = tile[tx][ty + i];
}

// ---------------------------------------------------------------------------
// w_proj transpose: [1024][1024] f32 -> bf16 BT[n][k] = w[k][n] stored in the
// DEAD V-slot columns of qkv: dst = qkv + 2048, row pitch 3072, rows 0..1023.
// ---------------------------------------------------------------------------
__global__ __launch_bounds__(256) void transpose_wp(const float* __restrict__ w,
                                                    u16* __restrict__ dst) {
    __shared__ float tile[32][33];
    const int nb = blockIdx.x * 32, kb = blockIdx.y * 32;
    const int tx = threadIdx.x & 31, ty = threadIdx.x >> 5;  // 32 x 8
#pragma unroll
    for (int i = 0; i < 32; i += 8)
        tile[ty + i][tx] = w[(long)(kb + ty + i) * 1024 + nb + tx];
    __syncthreads();
#pragma unroll
    for (int i = 0; i < 32; i += 8)
        dst[(long)(nb + ty + i) * 3072 + kb + tx] = f2bf(tile[tx][ty + i]);
}

// ---------------------------------------------------------------------------
// Shared ring-GEMM machinery: 128x128 tile, BK=32, 3-slot LDS ring with
// counted vmcnt (T4). Per step: wait vmcnt(4) (tile-t loads, issued 2 steps
// earlier), ONE barrier, issue tile t+2, ds_read + MFMA. vmcnt never 0 in
// the loop. Race audit in R7 notes.
// R10: MFMA shape switched to 32x32x16 (4060 vs 3378 FLOP/cyc; half the
// instructions). Per wave 64x64 = f32x16 acc[2][2], 8 MFMA/step. Fragment
// layouts as verified in attn: A[m=lane&31][k=8*hi+j], C/D col=lane&31,
// row=(r&3)+8*(r>>2)+4*hi. XCD-aware bid swizzle (T1, nwg%8==0 bijective).
// ---------------------------------------------------------------------------
#define G_STAGE(KOFF, SLOT)                                                   \
    gload_lds16(Ag + (KOFF), &As[(SLOT)*4096 + wbase]);                       \
    gload_lds16(Ag + (KOFF) + (long)16 * lda, &As[(SLOT)*4096 + wbase + 512]);\
    gload_lds16(Bg + (KOFF), &Bs[(SLOT)*4096 + wbase]);                       \
    gload_lds16(Bg + (KOFF) + (long)16 * ldbv, &Bs[(SLOT)*4096 + wbase + 512]);

#define G_COMPUTE(SLOT)                                                       \
    {                                                                         \
        short8 af[2][2], bf[2][2];                                            \
        _Pragma("unroll")                                                     \
        for (int mt = 0; mt < 2; ++mt)                                        \
            _Pragma("unroll")                                                 \
            for (int kh = 0; kh < 2; ++kh)                                    \
                af[mt][kh] = *(const short8*)&As[(SLOT)*4096 +                \
                    (wm + mt*32 + cc)*32 + kh*16 + hi*8];                     \
        _Pragma("unroll")                                                     \
        for (int nt = 0; nt < 2; ++nt)                                        \
            _Pragma("unroll")                                                 \
            for (int kh = 0; kh < 2; ++kh)                                    \
                bf[nt][kh] = *(const short8*)&Bs[(SLOT)*4096 +                \
                    (wn + nt*32 + cc)*32 + kh*16 + hi*8];                     \
        _Pragma("unroll")                                                     \
        for (int mt = 0; mt < 2; ++mt)                                        \
            _Pragma("unroll")                                                 \
            for (int nt = 0; nt < 2; ++nt) {                                  \
                acc[mt][nt] = __builtin_amdgcn_mfma_f32_32x32x16_bf16(        \
                    af[mt][0], bf[nt][0], acc[mt][nt], 0, 0, 0);              \
                acc[mt][nt] = __builtin_amdgcn_mfma_f32_32x32x16_bf16(        \
                    af[mt][1], bf[nt][1], acc[mt][nt], 0, 0, 0);              \
            }                                                                 \
    }

#define G_RING_LOOP                                                           \
    G_STAGE(0, 0);                                                            \
    G_STAGE(32, 1);                                                           \
    int slot = 0, s2 = 2;                                                     \
    for (int kb = 0; kb + 64 < K; kb += 32) {                                 \
        asm volatile("s_waitcnt vmcnt(4)" ::: "memory");                      \
        __builtin_amdgcn_s_barrier();                                         \
        G_STAGE(kb + 64, s2);                                                 \
        G_COMPUTE(slot);                                                      \
        slot = (slot + 1 == 3) ? 0 : slot + 1;                                \
        s2 = (s2 + 1 == 3) ? 0 : s2 + 1;                                      \
    }                                                                         \
    asm volatile("s_waitcnt vmcnt(4)" ::: "memory");                          \
    __builtin_amdgcn_s_barrier();                                             \
    G_COMPUTE(slot);                                                          \
    slot = (slot + 1 == 3) ? 0 : slot + 1;                                    \
    asm volatile("s_waitcnt vmcnt(0)" ::: "memory");                          \
    __builtin_amdgcn_s_barrier();                                             \
    G_COMPUTE(slot);

// XCD-aware bijective bid swizzle (requires nwg % 8 == 0)
#define G_BID_SWZ                                                             \
    const int nwg = gridDim.x * gridDim.y;                                    \
    const int bid0 = blockIdx.y * gridDim.x + blockIdx.x;                     \
    const int sb = (bid0 & 7) * (nwg >> 3) + (bid0 >> 3);                     \
    const int bx = sb % gridDim.x, by = sb / gridDim.x;

// ---------------------------------------------------------------------------
// GEMM1: C[M,N](bf16) = A[M,K](bf16, lda) @ BT[N,K](bf16)^T + bias(f32)
// K-slot columns [1024,2048) pre-scaled by K_SCALE (softmax fold).
// ---------------------------------------------------------------------------
__global__ __launch_bounds__(256, 3) void gemm_bf16_bt(
    const u16* __restrict__ A, int lda, const u16* __restrict__ BT,
    const float* __restrict__ bias, u16* __restrict__ C,
    int M, int N, int K) {
    __shared__ __align__(16) u16 As[3 * 128 * 32];   // 3 x 8KB ring
    __shared__ __align__(16) u16 Bs[3 * 128 * 32];
    const int tid = threadIdx.x;
    const int wv = tid >> 6, lane = tid & 63;
    const int cc = lane & 31, hi = lane >> 5;
    const int wm = (wv >> 1) * 64, wn = (wv & 1) * 64;
    G_BID_SWZ
    const long m0 = (long)by * 128;
    const long n0 = (long)bx * 128;

    const u16* Ag = A + (m0 + wv * 32 + (lane >> 2)) * (long)lda + (lane & 3) * 8;
    const u16* Bg = BT + (n0 + wv * 32 + (lane >> 2)) * (long)K + (lane & 3) * 8;
    const long ldbv = K;
    const int wbase = wv * 1024;

    f32x16 acc[2][2];
#pragma unroll
    for (int i = 0; i < 2; ++i)
#pragma unroll
        for (int j = 0; j < 2; ++j)
#pragma unroll
            for (int r = 0; r < 16; ++r) acc[i][j][r] = 0.f;

    G_RING_LOOP

#pragma unroll
    for (int nt = 0; nt < 2; ++nt) {
        const long col = n0 + wn + nt * 32 + cc;
        const float bv = bias[col];
        const float scl = (col >= 1024 && col < 2048) ? K_SCALE : 1.0f;
#pragma unroll
        for (int mt = 0; mt < 2; ++mt)
#pragma unroll
            for (int r = 0; r < 16; ++r) {
                const long row = m0 + wm + mt * 32 + (r & 3) + 8 * (r >> 2) + 4 * hi;
                C[row * N + col] = f2bf((acc[mt][nt][r] + bv) * scl);
            }
    }
}

// ---------------------------------------------------------------------------
// GEMM2: C[M,N](f32) = A[M,K](bf16, lda) @ BT[N,K](bf16, ldb)^T + bias(f32)
// Same ring as GEMM1; BT = pre-transposed w_proj in qkv V-slots (ldb=3072).
// ---------------------------------------------------------------------------
__global__ __launch_bounds__(256, 3) void gemm_bt2(
    const u16* __restrict__ A, int lda, const u16* __restrict__ BT, int ldb,
    const float* __restrict__ bias, float* __restrict__ C,
    int M, int N, int K) {
    __shared__ __align__(16) u16 As[3 * 128 * 32];
    __shared__ __align__(16) u16 Bs[3 * 128 * 32];
    const int tid = threadIdx.x;
    const int wv = tid >> 6, lane = tid & 63;
    const int cc = lane & 31, hi = lane >> 5;
    const int wm = (wv >> 1) * 64, wn = (wv & 1) * 64;
    G_BID_SWZ
    const long m0 = (long)by * 128;
    const long n0 = (long)bx * 128;

    const u16* Ag = A + (m0 + wv * 32 + (lane >> 2)) * (long)lda + (lane & 3) * 8;
    const u16* Bg = BT + (n0 + wv * 32 + (lane >> 2)) * (long)ldb + (lane & 3) * 8;
    const long ldbv = ldb;
    const int wbase = wv * 1024;

    f32x16 acc[2][2];
#pragma unroll
    for (int i = 0; i < 2; ++i)
#pragma unroll
        for (int j = 0; j < 2; ++j)
#pragma unroll
            for (int r = 0; r < 16; ++r) acc[i][j][r] = 0.f;

    G_RING_LOOP

#pragma unroll
    for (int nt = 0; nt < 2; ++nt) {
        const long col = n0 + wn + nt * 32 + cc;
        const float bv = bias[col];
#pragma unroll
        for (int mt = 0; mt < 2; ++mt)
#pragma unroll
            for (int r = 0; r < 16; ++r) {
                const long row = m0 + wm + mt * 32 + (r & 3) + 8 * (r >> 2) + 4 * hi;
                C[row * N + col] = acc[mt][nt][r] + bv;
            }
    }
}

// ---------------------------------------------------------------------------
// Flash attention (causal), bf16, in-register softmax (m214/T12 structure).
//   - 4 waves x 32 queries (qtile = 128), grid 64 x 8 paired (15-by, by).
//   - 64-key STAGED tiles (two 32-key compute halves per stage).
//   - swapped QK^T on 32x32x16 MFMA: S[key][q]; P lane-local per q-column.
//   - P -> PV A-frag in registers: 8 cvt_pk + 4 permlane32_swap per half.
//   - softmax scale pre-folded into K (GEMM1 epilogue); pe = exp2(s).
//   - s_setprio(1) around MFMA clusters (T5).
// Output written into the Q slots of qkv (race-free: disjoint q-ownership).
// ---------------------------------------------------------------------------
#define AT_T 2048

__global__ __launch_bounds__(256) void attn_kernel(u16* __restrict__ qkv,
                                                   const u16* __restrict__ vT) {
    __shared__ u16 Kt[2][64 * 72];   // [key][d]  tile, pitch 72
    __shared__ u16 Vt[2][64 * 72];   // [d][key]  tile, pitch 72
    const int tid = threadIdx.x;
    const int wv = tid >> 6, lane = tid & 63;
    const int hi = lane >> 5, cc = lane & 31;
    const int bh = blockIdx.x;
    const int b = bh >> 4, h = bh & 15;
    const long rowbase = (long)b * AT_T;
    const long cbase = (long)h * 64;

    // staging geometry: thread covers rows (r, r+32), 8 chunks of 8 per row
    const int srow = tid >> 3, sc = tid & 7;  // 32 rows x 8 chunks, x2 rows
    const u16* Kg = qkv + (rowbase + srow) * 3072 + 1024 + cbase + sc * 8;
    const u16* Vg = vT + ((long)bh * 64 + srow) * 2048 + sc * 8;
    const int kLo = srow * 72 + sc * 8, kHi = (srow + 32) * 72 + sc * 8;

    // ones B-fragment: column 0 accumulates row sums
    short8 ones;
#pragma unroll
    for (int j = 0; j < 8; ++j) ones[j] = (cc == 0) ? (short)0x3F80 : (short)0;

    f32x16 z16;
#pragma unroll
    for (int r = 0; r < 16; ++r) z16[r] = 0.f;

    for (int pass = 0; pass < 2; ++pass) {
        const int qt = (pass == 0) ? (15 - (int)blockIdx.y) : (int)blockIdx.y;
        const int qw = qt * 128 + wv * 32;  // this wave's 32 queries
        const int nkb = 2 * qt + 2;         // staged 64-key tiles

        // Q as B-fragment: lane holds Q[q = cc][d = ks*16 + hi*8 + j]
        short8 qf[4];
#pragma unroll
        for (int ks = 0; ks < 4; ++ks)
            qf[ks] = *(const short8*)&qkv[(rowbase + qw + cc) * 3072 + cbase + ks * 16 + hi * 8];

        f32x16 accO0, accO1, accL;
#pragma unroll
        for (int r = 0; r < 16; ++r) { accO0[r] = 0.f; accO1[r] = 0.f; accL[r] = 0.f; }

        // preload tile 0 into buf 0
        {
            *(short8*)&Kt[0][kLo] = *(const short8*)Kg;
            *(short8*)&Kt[0][kHi] = *(const short8*)(Kg + (long)32 * 3072);
            *(short8*)&Vt[0][kLo] = *(const short8*)Vg;
            *(short8*)&Vt[0][kHi] = *(const short8*)(Vg + (long)32 * 2048);
        }
        __syncthreads();

        int p = 0;
        for (int kb = 0; kb < nkb; ++kb) {
            const int k0 = kb * 64;
            const bool more = (kb + 1) < nkb;
            short8 kn0, kn1, vn0, vn1;
            if (more) {
                kn0 = *(const short8*)(Kg + (long)(k0 + 64) * 3072);
                kn1 = *(const short8*)(Kg + (long)(k0 + 96) * 3072);
                vn0 = *(const short8*)(Vg + k0 + 64);
                vn1 = *(const short8*)(Vg + (long)32 * 2048 + k0 + 64);
            }

#pragma unroll
            for (int hh = 0; hh < 2; ++hh) {
                const int kh = k0 + 32 * hh;
                if (kh <= qw) {  // half has unmasked work for this wave
                    // swapped QK^T: S[key][q], A = K rows (32hh + cc)
                    f32x16 s;
                    __builtin_amdgcn_s_setprio(1);
                    {
                        short8 kf = *(const short8*)&Kt[p][(32 * hh + cc) * 72 + hi * 8];
                        s = __builtin_amdgcn_mfma_f32_32x32x16_bf16(kf, qf[0], z16, 0, 0, 0);
                    }
#pragma unroll
                    for (int ks = 1; ks < 4; ++ks) {
                        short8 kf = *(const short8*)&Kt[p][(32 * hh + cc) * 72 + ks * 16 + hi * 8];
                        s = __builtin_amdgcn_mfma_f32_32x32x16_bf16(kf, qf[ks], s, 0, 0, 0);
                    }
                    __builtin_amdgcn_s_setprio(0);
                    // pe = exp2(s)  (K pre-scaled by 0.125*log2e; no bias)
                    float pe[16];
                    if (kh == qw) {  // diagonal half: mask key > q
#pragma unroll
                        for (int r = 0; r < 16; ++r) {
                            const int key = (r & 3) + 8 * (r >> 2) + 4 * hi;
                            const float e = EXP2F(s[r]);
                            pe[r] = (key <= cc) ? e : 0.f;
                        }
                    } else {
#pragma unroll
                        for (int r = 0; r < 16; ++r) pe[r] = EXP2F(s[r]);
                    }

                    // in-register P -> PV A-fragment (two 16-key slots)
                    short8 pa[2];
#pragma unroll
                    for (int ks = 0; ks < 2; ++ks) {
                        u32 wA = cvt_pk_bf16(pe[8 * ks + 0], pe[8 * ks + 1]);
                        u32 wB = cvt_pk_bf16(pe[8 * ks + 2], pe[8 * ks + 3]);
                        u32 wC = cvt_pk_bf16(pe[8 * ks + 4], pe[8 * ks + 5]);
                        u32 wD = cvt_pk_bf16(pe[8 * ks + 6], pe[8 * ks + 7]);
                        pswap(wA, wC);  // -> dword0, dword2
                        pswap(wB, wD);  // -> dword1, dword3
                        union { u32 d[4]; short8 v; } u;
                        u.d[0] = wA; u.d[1] = wB; u.d[2] = wC; u.d[3] = wD;
                        pa[ks] = u.v;
                    }

                    // row sums (column 0 of accL) + PV
                    __builtin_amdgcn_s_setprio(1);
                    accL = __builtin_amdgcn_mfma_f32_32x32x16_bf16(pa[0], ones, accL, 0, 0, 0);
                    accL = __builtin_amdgcn_mfma_f32_32x32x16_bf16(pa[1], ones, accL, 0, 0, 0);
#pragma unroll
                    for (int ks = 0; ks < 2; ++ks) {
                        short8 vf0 = *(const short8*)&Vt[p][cc * 72 + 32 * hh + ks * 16 + hi * 8];
                        short8 vf1 = *(const short8*)&Vt[p][(32 + cc) * 72 + 32 * hh + ks * 16 + hi * 8];
                        accO0 = __builtin_amdgcn_mfma_f32_32x32x16_bf16(pa[ks], vf0, accO0, 0, 0, 0);
                        accO1 = __builtin_amdgcn_mfma_f32_32x32x16_bf16(pa[ks], vf1, accO1, 0, 0, 0);
                    }
                    __builtin_amdgcn_s_setprio(0);
                }
            }

            // write prefetched tile into the other buffer
            if (more) {
                *(short8*)&Kt[p ^ 1][kLo] = kn0;
                *(short8*)&Kt[p ^ 1][kHi] = kn1;
                *(short8*)&Vt[p ^ 1][kLo] = vn0;
                *(short8*)&Vt[p ^ 1][kHi] = vn1;
            }
            __syncthreads();
            p ^= 1;
        }

        // normalize + write into Q slots.
        // accO{0,1}[r] = O[q = crow(r,hi)][d = {0,32} + cc];
        // l[q] lives at lane hi*32 (col 0), reg r.
#pragma unroll
        for (int r = 0; r < 16; ++r) {
            const float l = __shfl(accL[r], lane & 32);
            const float inv = 1.f / l;
            const int q = (r & 3) + 8 * (r >> 2) + 4 * hi;
            const long orow = (rowbase + qw + q) * 3072 + cbase;
            qkv[orow + cc] = f2bf(accO0[r] * inv);
            qkv[orow + 32 + cc] = f2bf(accO1[r] * inv);
        }
    }
}

// ---------------------------------------------------------------------------
extern "C" void kernel_launch(void* const* d_in, const int* in_sizes, int n_in,
                              void* d_out, int out_size, void* d_ws, size_t ws_size,
                              hipStream_t stream) {
    const float* x      = (const float*)d_in[0];
    const float* w_attn = (const float*)d_in[1];
    const float* b_attn = (const float*)d_in[2];
    const float* w_proj = (const float*)d_in[3];
    const float* b_proj = (const float*)d_in[4];
    float* out = (float*)d_out;

    u16* qkv = (u16*)d_ws;                      // [8192,3072] bf16 (50.33 MB)
    u16* xb  = (u16*)d_out;                     // [8192,1024] bf16 scratch (dies at GEMM1)
    u16* wTa = (u16*)((char*)d_out + 16777216); // [3072,1024] bf16 scratch (dies at GEMM1)
    u16* vT  = (u16*)d_out;                     // [64,64,2048] bf16 scratch (dies at GEMM2)
    u16* wTp = qkv + 2048;                      // [1024][1024] bf16 in dead V slots, pitch 3072

    prep_kernel<<<4096 + 3072, 256, 0, stream>>>(x, xb, w_attn, wTa);
    gemm_bf16_bt<<<dim3(3072 / 128, 8192 / 128), 256, 0, stream>>>(
        xb, 1024, wTa, b_attn, qkv, 8192, 3072, 1024);
    transpose_v<<<dim3(64, 2, 64), dim3(32, 8), 0, stream>>>(qkv, vT);
    transpose_wp<<<dim3(32, 32), 256, 0, stream>>>(w_proj, wTp);
    attn_kernel<<<dim3(64, 8), 256, 0, stream>>>(qkv, vT);
    gemm_bt2<<<dim3(1024 / 128, 8192 / 128), 256, 0, stream>>>(
        qkv, 3072, wTp, 3072, b_proj, out, 8192, 1024, 1024);
}

// Round 11
// 241.679 us; speedup vs baseline: 1.0961x; 1.0961x over previous
//
#include <hip/hip_runtime.h>

typedef __attribute__((ext_vector_type(8))) short short8;
typedef __attribute__((ext_vector_type(4))) short short4v;
typedef __attribute__((ext_vector_type(4))) float f32x4;
typedef __attribute__((ext_vector_type(16))) float f32x16;
typedef unsigned short u16;
typedef unsigned int u32;

__device__ __forceinline__ float bf2f(u16 u) {
    union { u32 i; float f; } x;
    x.i = ((u32)u) << 16;
    return x.f;
}

__device__ __forceinline__ u16 f2bf(float f) {
    union { float f; u32 i; } x;
    x.f = f;
    u32 r = x.i + 0x7fffu + ((x.i >> 16) & 1u);  // RNE
    return (u16)(r >> 16);
}

// packed f32x2 -> bf16x2 (RNE), one instruction
__device__ __forceinline__ u32 cvt_pk_bf16(float lo, float hi) {
    u32 d;
    asm("v_cvt_pk_bf16_f32 %0, %1, %2" : "=v"(d) : "v"(lo), "v"(hi));
    return d;
}

// async global->LDS DMA, 16 B/lane. LDS dest = wave-uniform base + lane*16.
__device__ __forceinline__ void gload_lds16(const u16* g, u16* l) {
    __builtin_amdgcn_global_load_lds(
        (const __attribute__((address_space(1))) void*)g,
        (__attribute__((address_space(3))) void*)l, 16, 0, 0);
}

// after pswap(a,b):  a' = lane<32 ? a(own) : b(lane-32)
//                    b' = lane<32 ? a(lane+32) : b(own)
__device__ __forceinline__ void pswap(u32& a, u32& b) {
#if __has_builtin(__builtin_amdgcn_permlane32_swap)
    auto r = __builtin_amdgcn_permlane32_swap(a, b, false, false);
    a = r[0];
    b = r[1];
#else
    const int l = (int)(threadIdx.x & 63);
    const u32 ax = __shfl(a, l ^ 32);
    const u32 bx = __shfl(b, l ^ 32);
    a = (l < 32) ? a : bx;
    b = (l < 32) ? ax : b;
#endif
}

#if __has_builtin(__builtin_amdgcn_exp2f)
#define EXP2F(x) __builtin_amdgcn_exp2f(x)
#else
#define EXP2F(x) exp2f(x)
#endif

// softmax scale folded into K at GEMM1 epilogue: 0.125 * log2(e)
#define K_SCALE 0.18033688f

// ---------------------------------------------------------------------------
// Fused pre-pass: blocks [0,4096): fp32->bf16 convert of x (8192x1024);
// blocks [4096,7168): w_attn [1024][3072] f32 -> wTa [3072][1024] bf16.
// ---------------------------------------------------------------------------
__global__ __launch_bounds__(256) void prep_kernel(const float* __restrict__ x,
                                                   u16* __restrict__ xb,
                                                   const float* __restrict__ w_attn,
                                                   u16* __restrict__ wTa) {
    __shared__ float tile[32][33];
    const int tid = threadIdx.x;
    if (blockIdx.x < 4096) {
        const long i = ((long)blockIdx.x * 256 + tid) * 8;
        f32x4 v0 = *(const f32x4*)(x + i);
        f32x4 v1 = *(const f32x4*)(x + i + 4);
        short8 o;
#pragma unroll
        for (int j = 0; j < 4; ++j) o[j] = (short)f2bf(v0[j]);
#pragma unroll
        for (int j = 0; j < 4; ++j) o[4 + j] = (short)f2bf(v1[j]);
        *(short8*)(xb + i) = o;
    } else {
        const int bid = blockIdx.x - 4096;
        const int nb = (bid % 96) * 32, kb = (bid / 96) * 32;
        const int tx = tid & 31, ty = tid >> 5;  // 32 x 8
#pragma unroll
        for (int i = 0; i < 32; i += 8)
            tile[ty + i][tx] = w_attn[(long)(kb + ty + i) * 3072 + nb + tx];
        __syncthreads();
#pragma unroll
        for (int i = 0; i < 32; i += 8)
            wTa[(long)(nb + ty + i) * 1024 + kb + tx] = f2bf(tile[tx][ty + i]);
    }
}

// ---------------------------------------------------------------------------
// V transpose (FALLBACK ONLY, if ws too small for fused path):
// qkv V slots [b*2048+t][2048 + h*64 + d] -> vT[bh][d][t]
// ---------------------------------------------------------------------------
__global__ __launch_bounds__(256) void transpose_v(const u16* __restrict__ qkv,
                                                   u16* __restrict__ vT) {
    __shared__ u16 tile[32][33];
    const int tb = blockIdx.x * 32;  // t
    const int db = blockIdx.y * 32;  // d
    const int bh = blockIdx.z;
    const int b = bh >> 4, h = bh & 15;
    const int tx = threadIdx.x, ty = threadIdx.y;  // 32 x 8
#pragma unroll
    for (int i = 0; i < 32; i += 8)
        tile[ty + i][tx] = qkv[((long)b * 2048 + tb + ty + i) * 3072 + 2048 + h * 64 + db + tx];
    __syncthreads();
#pragma unroll
    for (int i = 0; i < 32; i += 8)
        vT[((long)bh * 64 + db + ty + i) * 2048 + tb + tx] = tile[tx][ty + i];
}

// ---------------------------------------------------------------------------
// w_proj transpose: [1024][1024] f32 -> bf16 BT[n][k] = w[k][n] stored in the
// DEAD V-slot columns of qkv: dst = qkv + 2048, row pitch 3072, rows 0..1023.
// ---------------------------------------------------------------------------
__global__ __launch_bounds__(256) void transpose_wp(const float* __restrict__ w,
                                                    u16* __restrict__ dst) {
    __shared__ float tile[32][33];
    const int nb = blockIdx.x * 32, kb = blockIdx.y * 32;
    const int tx = threadIdx.x & 31, ty = threadIdx.x >> 5;  // 32 x 8
#pragma unroll
    for (int i = 0; i < 32; i += 8)
        tile[ty + i][tx] = w[(long)(kb + ty + i) * 1024 + nb + tx];
    __syncthreads();
#pragma unroll
    for (int i = 0; i < 32; i += 8)
        dst[(long)(nb + ty + i) * 3072 + kb + tx] = f2bf(tile[tx][ty + i]);
}

// ---------------------------------------------------------------------------
// Shared ring-GEMM machinery (round-8 verified form): 128x128 tile, BK=32,
// 3-slot LDS ring with counted vmcnt (T4), 16x16x32 MFMA (round-10's 32x32
// shape REVERTED: its fragment reads were 8-way bank conflicted, 3x the
// conflict count, +12 us). XCD-aware bid swizzle (T1, nwg%8==0 bijective).
// Per step: wait vmcnt(4), ONE barrier, issue tile t+2, ds_read + 16 MFMA.
// ---------------------------------------------------------------------------
#define G_STAGE(KOFF, SLOT)                                                   \
    gload_lds16(Ag + (KOFF), &As[(SLOT)*4096 + wbase]);                       \
    gload_lds16(Ag + (KOFF) + (long)16 * lda, &As[(SLOT)*4096 + wbase + 512]);\
    gload_lds16(Bg + (KOFF), &Bs[(SLOT)*4096 + wbase]);                       \
    gload_lds16(Bg + (KOFF) + (long)16 * ldbv, &Bs[(SLOT)*4096 + wbase + 512]);

#define G_COMPUTE(SLOT)                                                       \
    {                                                                         \
        short8 af[4], bf[4];                                                  \
        _Pragma("unroll")                                                     \
        for (int mt = 0; mt < 4; ++mt)                                        \
            af[mt] = *(const short8*)&As[(SLOT)*4096 + (wm + mt*16 + L)*32 + quad*8]; \
        _Pragma("unroll")                                                     \
        for (int nt = 0; nt < 4; ++nt)                                        \
            bf[nt] = *(const short8*)&Bs[(SLOT)*4096 + (wn + nt*16 + L)*32 + quad*8]; \
        _Pragma("unroll")                                                     \
        for (int mt = 0; mt < 4; ++mt)                                        \
            _Pragma("unroll")                                                 \
            for (int nt = 0; nt < 4; ++nt)                                    \
                acc[mt][nt] = __builtin_amdgcn_mfma_f32_16x16x32_bf16(        \
                    af[mt], bf[nt], acc[mt][nt], 0, 0, 0);                    \
    }

#define G_RING_LOOP                                                           \
    G_STAGE(0, 0);                                                            \
    G_STAGE(32, 1);                                                           \
    int slot = 0, s2 = 2;                                                     \
    for (int kb = 0; kb + 64 < K; kb += 32) {                                 \
        asm volatile("s_waitcnt vmcnt(4)" ::: "memory");                      \
        __builtin_amdgcn_s_barrier();                                         \
        G_STAGE(kb + 64, s2);                                                 \
        G_COMPUTE(slot);                                                      \
        slot = (slot + 1 == 3) ? 0 : slot + 1;                                \
        s2 = (s2 + 1 == 3) ? 0 : s2 + 1;                                      \
    }                                                                         \
    asm volatile("s_waitcnt vmcnt(4)" ::: "memory");                          \
    __builtin_amdgcn_s_barrier();                                             \
    G_COMPUTE(slot);                                                          \
    slot = (slot + 1 == 3) ? 0 : slot + 1;                                    \
    asm volatile("s_waitcnt vmcnt(0)" ::: "memory");                          \
    __builtin_amdgcn_s_barrier();                                             \
    G_COMPUTE(slot);

// XCD-aware bijective bid swizzle (requires nwg % 8 == 0)
#define G_BID_SWZ                                                             \
    const int nwg = gridDim.x * gridDim.y;                                    \
    const int bid0 = blockIdx.y * gridDim.x + blockIdx.x;                     \
    const int sb = (bid0 & 7) * (nwg >> 3) + (bid0 >> 3);                     \
    const int bx = sb % gridDim.x, by = sb / gridDim.x;

// ---------------------------------------------------------------------------
// GEMM1: C[M,N](bf16) = A[M,K](bf16, lda) @ BT[N,K](bf16)^T + bias(f32)
// K-slot columns [1024,2048) pre-scaled by K_SCALE (softmax fold).
// FUSED V-TRANSPOSE epilogue (vTd != nullptr): for V-range n-blocks
// (n0 >= 2048), the 128x128 tile is transposed via the (now free) LDS ring
// and written directly as vT[(b*16+h)*64+d][t] (t-contiguous, coalesced) —
// qkv V columns are never written, and the transpose_v kernel + its 64 MB
// HBM round trip disappear.
// ---------------------------------------------------------------------------
__global__ __launch_bounds__(256, 3) void gemm_bf16_bt(
    const u16* __restrict__ A, int lda, const u16* __restrict__ BT,
    const float* __restrict__ bias, u16* __restrict__ C,
    u16* __restrict__ vTd, int M, int N, int K) {
    __shared__ __align__(16) u16 RingLDS[2 * 3 * 4096];   // 48 KB
    u16* const As = RingLDS;
    u16* const Bs = RingLDS + 3 * 4096;
    const int tid = threadIdx.x;
    const int wv = tid >> 6, lane = tid & 63, quad = lane >> 4, L = lane & 15;
    const int wm = (wv >> 1) * 64, wn = (wv & 1) * 64;
    G_BID_SWZ
    const long m0 = (long)by * 128;
    const long n0 = (long)bx * 128;

    const u16* Ag = A + (m0 + wv * 32 + (lane >> 2)) * (long)lda + (lane & 3) * 8;
    const u16* Bg = BT + (n0 + wv * 32 + (lane >> 2)) * (long)K + (lane & 3) * 8;
    const long ldbv = K;
    const int wbase = wv * 1024;

    f32x4 zero4 = {0.f, 0.f, 0.f, 0.f};
    f32x4 acc[4][4];
#pragma unroll
    for (int i = 0; i < 4; ++i)
#pragma unroll
        for (int j = 0; j < 4; ++j) acc[i][j] = zero4;

    G_RING_LOOP

    if (vTd != nullptr && n0 >= 2048) {
        // ---- fused V transpose path (block-uniform branch) ----
        __syncthreads();                 // ring reads complete; LDS reusable
        u16* Tl = RingLDS;               // [128][136] u16 = 34816 B (< 48 KB)
#pragma unroll
        for (int nt = 0; nt < 4; ++nt) {
            const int cl = wn + nt * 16 + L;           // col_local 0..127
            const float bv = bias[n0 + cl];
#pragma unroll
            for (int mt = 0; mt < 4; ++mt) {
                short4v pv;
#pragma unroll
                for (int r = 0; r < 4; ++r) pv[r] = (short)f2bf(acc[mt][nt][r] + bv);
                *(short4v*)&Tl[cl * 136 + wm + mt * 16 + quad * 4] = pv;
            }
        }
        __syncthreads();
        // write out: thread (j = tid>>1, half = tid&1) emits 64 contiguous t
        const int j = tid >> 1, half = tid & 1;
        const int colg = (int)(n0 - 2048) + j;         // 0..1023
        const int h = colg >> 6, d = colg & 63;
        const long bq = m0 >> 11;                      // batch index
        const long t0 = (m0 & 2047) + half * 64;
        u16* dst = vTd + (((bq * 16 + h) * 64 + d) * 2048) + t0;
        const u16* src = &Tl[j * 136 + half * 64];
#pragma unroll
        for (int q8 = 0; q8 < 8; ++q8)
            *(short8*)(dst + q8 * 8) = *(const short8*)(src + q8 * 8);
    } else {
        // ---- normal C write (Q/K columns, or fallback mode) ----
#pragma unroll
        for (int nt = 0; nt < 4; ++nt) {
            const long col = n0 + wn + nt * 16 + L;
            const float bv = bias[col];
            const float scl = (col >= 1024 && col < 2048) ? K_SCALE : 1.0f;
#pragma unroll
            for (int mt = 0; mt < 4; ++mt)
#pragma unroll
                for (int r = 0; r < 4; ++r) {
                    const long row = m0 + wm + mt * 16 + quad * 4 + r;
                    C[row * N + col] = f2bf((acc[mt][nt][r] + bv) * scl);
                }
        }
    }
}

// ---------------------------------------------------------------------------
// GEMM2: C[M,N](f32) = A[M,K](bf16, lda) @ BT[N,K](bf16, ldb)^T + bias(f32)
// Same ring as GEMM1; BT = pre-transposed w_proj in qkv V-slots (ldb=3072).
// ---------------------------------------------------------------------------
__global__ __launch_bounds__(256, 3) void gemm_bt2(
    const u16* __restrict__ A, int lda, const u16* __restrict__ BT, int ldb,
    const float* __restrict__ bias, float* __restrict__ C,
    int M, int N, int K) {
    __shared__ __align__(16) u16 RingLDS[2 * 3 * 4096];
    u16* const As = RingLDS;
    u16* const Bs = RingLDS + 3 * 4096;
    const int tid = threadIdx.x;
    const int wv = tid >> 6, lane = tid & 63, quad = lane >> 4, L = lane & 15;
    const int wm = (wv >> 1) * 64, wn = (wv & 1) * 64;
    G_BID_SWZ
    const long m0 = (long)by * 128;
    const long n0 = (long)bx * 128;

    const u16* Ag = A + (m0 + wv * 32 + (lane >> 2)) * (long)lda + (lane & 3) * 8;
    const u16* Bg = BT + (n0 + wv * 32 + (lane >> 2)) * (long)ldb + (lane & 3) * 8;
    const long ldbv = ldb;
    const int wbase = wv * 1024;

    f32x4 zero4 = {0.f, 0.f, 0.f, 0.f};
    f32x4 acc[4][4];
#pragma unroll
    for (int i = 0; i < 4; ++i)
#pragma unroll
        for (int j = 0; j < 4; ++j) acc[i][j] = zero4;

    G_RING_LOOP

#pragma unroll
    for (int nt = 0; nt < 4; ++nt) {
        const long col = n0 + wn + nt * 16 + L;
        const float bv = bias[col];
#pragma unroll
        for (int mt = 0; mt < 4; ++mt)
#pragma unroll
            for (int r = 0; r < 4; ++r) {
                const long row = m0 + wm + mt * 16 + quad * 4 + r;
                C[row * N + col] = acc[mt][nt][r] + bv;
            }
    }
}

// ---------------------------------------------------------------------------
// Flash attention (causal), bf16, in-register softmax (m214/T12 structure).
//   - 4 waves x 32 queries (qtile = 128), grid 64 x 8 paired (15-by, by).
//   - 64-key STAGED tiles (two 32-key compute halves per stage).
//   - swapped QK^T on 32x32x16 MFMA: S[key][q]; P lane-local per q-column.
//   - P -> PV A-frag in registers: 8 cvt_pk + 4 permlane32_swap per half.
//   - softmax scale pre-folded into K (GEMM1 epilogue); pe = exp2(s).
//   - s_setprio(1) around MFMA clusters (T5).
// Output written into the Q slots of qkv (race-free: disjoint q-ownership).
// ---------------------------------------------------------------------------
#define AT_T 2048

__global__ __launch_bounds__(256) void attn_kernel(u16* __restrict__ qkv,
                                                   const u16* __restrict__ vT) {
    __shared__ u16 Kt[2][64 * 72];   // [key][d]  tile, pitch 72
    __shared__ u16 Vt[2][64 * 72];   // [d][key]  tile, pitch 72
    const int tid = threadIdx.x;
    const int wv = tid >> 6, lane = tid & 63;
    const int hi = lane >> 5, cc = lane & 31;
    const int bh = blockIdx.x;
    const int b = bh >> 4, h = bh & 15;
    const long rowbase = (long)b * AT_T;
    const long cbase = (long)h * 64;

    // staging geometry: thread covers rows (r, r+32), 8 chunks of 8 per row
    const int srow = tid >> 3, sc = tid & 7;  // 32 rows x 8 chunks, x2 rows
    const u16* Kg = qkv + (rowbase + srow) * 3072 + 1024 + cbase + sc * 8;
    const u16* Vg = vT + ((long)bh * 64 + srow) * 2048 + sc * 8;
    const int kLo = srow * 72 + sc * 8, kHi = (srow + 32) * 72 + sc * 8;

    // ones B-fragment: column 0 accumulates row sums
    short8 ones;
#pragma unroll
    for (int j = 0; j < 8; ++j) ones[j] = (cc == 0) ? (short)0x3F80 : (short)0;

    f32x16 z16;
#pragma unroll
    for (int r = 0; r < 16; ++r) z16[r] = 0.f;

    for (int pass = 0; pass < 2; ++pass) {
        const int qt = (pass == 0) ? (15 - (int)blockIdx.y) : (int)blockIdx.y;
        const int qw = qt * 128 + wv * 32;  // this wave's 32 queries
        const int nkb = 2 * qt + 2;         // staged 64-key tiles

        // Q as B-fragment: lane holds Q[q = cc][d = ks*16 + hi*8 + j]
        short8 qf[4];
#pragma unroll
        for (int ks = 0; ks < 4; ++ks)
            qf[ks] = *(const short8*)&qkv[(rowbase + qw + cc) * 3072 + cbase + ks * 16 + hi * 8];

        f32x16 accO0, accO1, accL;
#pragma unroll
        for (int r = 0; r < 16; ++r) { accO0[r] = 0.f; accO1[r] = 0.f; accL[r] = 0.f; }

        // preload tile 0 into buf 0
        {
            *(short8*)&Kt[0][kLo] = *(const short8*)Kg;
            *(short8*)&Kt[0][kHi] = *(const short8*)(Kg + (long)32 * 3072);
            *(short8*)&Vt[0][kLo] = *(const short8*)Vg;
            *(short8*)&Vt[0][kHi] = *(const short8*)(Vg + (long)32 * 2048);
        }
        __syncthreads();

        int p = 0;
        for (int kb = 0; kb < nkb; ++kb) {
            const int k0 = kb * 64;
            const bool more = (kb + 1) < nkb;
            short8 kn0, kn1, vn0, vn1;
            if (more) {
                kn0 = *(const short8*)(Kg + (long)(k0 + 64) * 3072);
                kn1 = *(const short8*)(Kg + (long)(k0 + 96) * 3072);
                vn0 = *(const short8*)(Vg + k0 + 64);
                vn1 = *(const short8*)(Vg + (long)32 * 2048 + k0 + 64);
            }

#pragma unroll
            for (int hh = 0; hh < 2; ++hh) {
                const int kh = k0 + 32 * hh;
                if (kh <= qw) {  // half has unmasked work for this wave
                    // swapped QK^T: S[key][q], A = K rows (32hh + cc)
                    f32x16 s;
                    __builtin_amdgcn_s_setprio(1);
                    {
                        short8 kf = *(const short8*)&Kt[p][(32 * hh + cc) * 72 + hi * 8];
                        s = __builtin_amdgcn_mfma_f32_32x32x16_bf16(kf, qf[0], z16, 0, 0, 0);
                    }
#pragma unroll
                    for (int ks = 1; ks < 4; ++ks) {
                        short8 kf = *(const short8*)&Kt[p][(32 * hh + cc) * 72 + ks * 16 + hi * 8];
                        s = __builtin_amdgcn_mfma_f32_32x32x16_bf16(kf, qf[ks], s, 0, 0, 0);
                    }
                    __builtin_amdgcn_s_setprio(0);
                    // pe = exp2(s)  (K pre-scaled by 0.125*log2e; no bias)
                    float pe[16];
                    if (kh == qw) {  // diagonal half: mask key > q
#pragma unroll
                        for (int r = 0; r < 16; ++r) {
                            const int key = (r & 3) + 8 * (r >> 2) + 4 * hi;
                            const float e = EXP2F(s[r]);
                            pe[r] = (key <= cc) ? e : 0.f;
                        }
                    } else {
#pragma unroll
                        for (int r = 0; r < 16; ++r) pe[r] = EXP2F(s[r]);
                    }

                    // in-register P -> PV A-fragment (two 16-key slots)
                    short8 pa[2];
#pragma unroll
                    for (int ks = 0; ks < 2; ++ks) {
                        u32 wA = cvt_pk_bf16(pe[8 * ks + 0], pe[8 * ks + 1]);
                        u32 wB = cvt_pk_bf16(pe[8 * ks + 2], pe[8 * ks + 3]);
                        u32 wC = cvt_pk_bf16(pe[8 * ks + 4], pe[8 * ks + 5]);
                        u32 wD = cvt_pk_bf16(pe[8 * ks + 6], pe[8 * ks + 7]);
                        pswap(wA, wC);  // -> dword0, dword2
                        pswap(wB, wD);  // -> dword1, dword3
                        union { u32 d[4]; short8 v; } u;
                        u.d[0] = wA; u.d[1] = wB; u.d[2] = wC; u.d[3] = wD;
                        pa[ks] = u.v;
                    }

                    // row sums (column 0 of accL) + PV
                    __builtin_amdgcn_s_setprio(1);
                    accL = __builtin_amdgcn_mfma_f32_32x32x16_bf16(pa[0], ones, accL, 0, 0, 0);
                    accL = __builtin_amdgcn_mfma_f32_32x32x16_bf16(pa[1], ones, accL, 0, 0, 0);
#pragma unroll
                    for (int ks = 0; ks < 2; ++ks) {
                        short8 vf0 = *(const short8*)&Vt[p][cc * 72 + 32 * hh + ks * 16 + hi * 8];
                        short8 vf1 = *(const short8*)&Vt[p][(32 + cc) * 72 + 32 * hh + ks * 16 + hi * 8];
                        accO0 = __builtin_amdgcn_mfma_f32_32x32x16_bf16(pa[ks], vf0, accO0, 0, 0, 0);
                        accO1 = __builtin_amdgcn_mfma_f32_32x32x16_bf16(pa[ks], vf1, accO1, 0, 0, 0);
                    }
                    __builtin_amdgcn_s_setprio(0);
                }
            }

            // write prefetched tile into the other buffer
            if (more) {
                *(short8*)&Kt[p ^ 1][kLo] = kn0;
                *(short8*)&Kt[p ^ 1][kHi] = kn1;
                *(short8*)&Vt[p ^ 1][kLo] = vn0;
                *(short8*)&Vt[p ^ 1][kHi] = vn1;
            }
            __syncthreads();
            p ^= 1;
        }

        // normalize + write into Q slots.
        // accO{0,1}[r] = O[q = crow(r,hi)][d = {0,32} + cc];
        // l[q] lives at lane hi*32 (col 0), reg r.
#pragma unroll
        for (int r = 0; r < 16; ++r) {
            const float l = __shfl(accL[r], lane & 32);
            const float inv = 1.f / l;
            const int q = (r & 3) + 8 * (r >> 2) + 4 * hi;
            const long orow = (rowbase + qw + q) * 3072 + cbase;
            qkv[orow + cc] = f2bf(accO0[r] * inv);
            qkv[orow + 32 + cc] = f2bf(accO1[r] * inv);
        }
    }
}

// ---------------------------------------------------------------------------
extern "C" void kernel_launch(void* const* d_in, const int* in_sizes, int n_in,
                              void* d_out, int out_size, void* d_ws, size_t ws_size,
                              hipStream_t stream) {
    const float* x      = (const float*)d_in[0];
    const float* w_attn = (const float*)d_in[1];
    const float* b_attn = (const float*)d_in[2];
    const float* w_proj = (const float*)d_in[3];
    const float* b_proj = (const float*)d_in[4];
    float* out = (float*)d_out;

    u16* qkv = (u16*)d_ws;                      // [8192,3072] bf16 (50.33 MB)
    u16* xb  = (u16*)d_out;                     // [8192,1024] bf16 scratch (dies at GEMM1)
    u16* wTa = (u16*)((char*)d_out + 16777216); // [3072,1024] bf16 scratch (dies at GEMM1)
    u16* wTp = qkv + 2048;                      // [1024][1024] bf16 in dead V slots, pitch 3072

    // Fused path: vT lives in d_ws after qkv (needs 50.33+16.78 = 67.1 MB).
    const bool fused_v = (ws_size >= (size_t)50331648 + 16777216);
    u16* vT = fused_v ? qkv + (size_t)8192 * 3072   // [64*64][2048] in d_ws
                      : (u16*)d_out;                // fallback scratch in d_out

    prep_kernel<<<4096 + 3072, 256, 0, stream>>>(x, xb, w_attn, wTa);
    gemm_bf16_bt<<<dim3(3072 / 128, 8192 / 128), 256, 0, stream>>>(
        xb, 1024, wTa, b_attn, qkv, fused_v ? vT : nullptr, 8192, 3072, 1024);
    if (!fused_v)
        transpose_v<<<dim3(64, 2, 64), dim3(32, 8), 0, stream>>>(qkv, vT);
    transpose_wp<<<dim3(32, 32), 256, 0, stream>>>(w_proj, wTp);
    attn_kernel<<<dim3(64, 8), 256, 0, stream>>>(qkv, vT);
    gemm_bt2<<<dim3(1024 / 128, 8192 / 128), 256, 0, stream>>>(
        qkv, 3072, wTp, 3072, b_proj, out, 8192, 1024, 1024);
}